// Round 1
// baseline (415.437 us; speedup 1.0000x reference)
//
#include <hip/hip_runtime.h>
#include <hip/hip_bf16.h>
#include <math.h>

#define D_MODEL 1024
#define NH      16
#define DK      64
#define SEQ     2048
#define BATCH   2

typedef float  f32x4  __attribute__((ext_vector_type(4)));
typedef __bf16 bf16x8 __attribute__((ext_vector_type(8)));
typedef unsigned short ushx4 __attribute__((ext_vector_type(4)));

__device__ inline unsigned short f2bf(float f) {
    unsigned int u = __float_as_uint(f);
    u += 0x7FFFu + ((u >> 16) & 1u);   // round-to-nearest-even
    return (unsigned short)(u >> 16);
}

// ---------------- RoPE tables: cos/sin [SEQ][DK/2] ----------------
__global__ void rope_tables_kernel(float* __restrict__ cost, float* __restrict__ sint) {
    int i = blockIdx.x * 256 + threadIdx.x;      // 2048*32 = 65536 total
    int pos = i >> 5, k = i & 31;
    float inv = powf(10000.0f, -2.0f * (float)k / 64.0f);
    float ang = (float)pos * inv;
    cost[i] = cosf(ang);
    sint[i] = sinf(ang);
}

// ---------------- GEMM: C[m][n] = sum_k A[m][k] * W[n][k] ----------------
// A fp32 [4096][1024], W fp32 [1024][1024]. bf16 MFMA 16x16x32.
// MODE 0: RoPE epilogue, store bf16 [b][h][s][dk]
// MODE 1: store bf16 V^T  [b][h][dk][s]
// MODE 2: store fp32 [m][n] (= [b][s][d_model])
template<int MODE>
__global__ __launch_bounds__(256) void gemm_kernel(
    const float* __restrict__ A, const float* __restrict__ W,
    void* __restrict__ outp, const int* __restrict__ tpos,
    const float* __restrict__ cost, const float* __restrict__ sint)
{
    constexpr int K = 1024;
    __shared__ unsigned short As[128 * 32];
    __shared__ unsigned short Bs[128 * 32];

    const int t  = threadIdx.x;
    const int m0 = blockIdx.x * 128, n0 = blockIdx.y * 128;
    const int lane = t & 63, wid = t >> 6;
    const int wm = wid >> 1, wn = wid & 1;       // 2x2 wave grid, 64x64 per wave
    const int lr = lane & 15, lg = lane >> 4;
    const int srow = t >> 1, scolb = (t & 1) * 16;

    f32x4 acc[4][4];
    #pragma unroll
    for (int i = 0; i < 4; i++)
        #pragma unroll
        for (int j = 0; j < 4; j++) acc[i][j] = 0.0f;

    const float* Arow = A + (size_t)(m0 + srow) * K + scolb;
    const float* Wrow = W + (size_t)(n0 + srow) * K + scolb;
    const int swzS = (srow >> 1) & 3;

    for (int k0 = 0; k0 < K; k0 += 32) {
        __syncthreads();
        #pragma unroll
        for (int j = 0; j < 4; j++) {
            f32x4 av = *(const f32x4*)(Arow + k0 + 4 * j);
            f32x4 wv = *(const f32x4*)(Wrow + k0 + 4 * j);
            int col = scolb + 4 * j;
            int sa = srow * 32 + (((col >> 3) ^ swzS) << 3) + (col & 7);
            ushx4 a4, w4;
            #pragma unroll
            for (int e = 0; e < 4; e++) { a4[e] = f2bf(av[e]); w4[e] = f2bf(wv[e]); }
            *(ushx4*)&As[sa] = a4;
            *(ushx4*)&Bs[sa] = w4;
        }
        __syncthreads();

        bf16x8 af[4], bfr[4];
        #pragma unroll
        for (int mi = 0; mi < 4; mi++) {
            int row = wm * 64 + mi * 16 + lr;
            af[mi] = *(const bf16x8*)&As[row * 32 + ((lg ^ ((row >> 1) & 3)) << 3)];
        }
        #pragma unroll
        for (int ni = 0; ni < 4; ni++) {
            int row = wn * 64 + ni * 16 + lr;
            bfr[ni] = *(const bf16x8*)&Bs[row * 32 + ((lg ^ ((row >> 1) & 3)) << 3)];
        }
        #pragma unroll
        for (int mi = 0; mi < 4; mi++)
            #pragma unroll
            for (int ni = 0; ni < 4; ni++)
                acc[mi][ni] = __builtin_amdgcn_mfma_f32_16x16x32_bf16(af[mi], bfr[ni], acc[mi][ni], 0, 0, 0);
    }

    #pragma unroll
    for (int mi = 0; mi < 4; mi++)
        #pragma unroll
        for (int ni = 0; ni < 4; ni++) {
            f32x4 v4 = acc[mi][ni];
            #pragma unroll
            for (int r = 0; r < 4; r++) {
                int m = m0 + wm * 64 + mi * 16 + lg * 4 + r;
                int n = n0 + wn * 64 + ni * 16 + lr;
                float v = v4[r];
                if constexpr (MODE == 2) {
                    ((float*)outp)[(size_t)m * D_MODEL + n] = v;
                } else if constexpr (MODE == 1) {
                    int b = m >> 11, s = m & 2047;
                    int h = n >> 6,  d = n & 63;
                    ((unsigned short*)outp)[(((size_t)b * NH + h) * DK + d) * SEQ + s] = f2bf(v);
                } else {
                    float vp = __shfl_xor(v, 1);   // pair partner (n parity == lane parity)
                    int b = m >> 11, s = m & 2047;
                    int h = n >> 6,  d = n & 63;
                    int tp = tpos[s];
                    float c  = cost[tp * 32 + (d >> 1)];
                    float sn = sint[tp * 32 + (d >> 1)];
                    float res = (d & 1) ? (vp * sn + v * c) : (v * c - vp * sn);
                    ((unsigned short*)outp)[(((size_t)b * NH + h) * SEQ + s) * DK + d] = f2bf(res);
                }
            }
        }
}

// ---------------- causal flash attention ----------------
// Q,K bf16 [b][h][s][dk]; VT bf16 [b][h][dk][s]; out fp32 [b][s][h*dk]
__global__ __launch_bounds__(256) void attn_kernel(
    const unsigned short* __restrict__ Q,
    const unsigned short* __restrict__ Km,
    const unsigned short* __restrict__ VT,
    float* __restrict__ aout)
{
    __shared__ unsigned short Pl[4 * 16 * 32];   // per-wave 16x32 P tile
    const int t = threadIdx.x, wid = t >> 6, lane = t & 63;
    const int lr = lane & 15, lg = lane >> 4;
    const int h = blockIdx.y, b = blockIdx.z, bh = b * NH + h;
    const int q0 = (blockIdx.x * 4 + wid) * 16;

    const unsigned short* Qb = Q  + (size_t)bh * SEQ * DK;
    const unsigned short* Kb = Km + (size_t)bh * SEQ * DK;
    const unsigned short* Vb = VT + (size_t)bh * DK * SEQ;

    bf16x8 aq0 = *(const bf16x8*)&Qb[(q0 + lr) * DK + lg * 8];
    bf16x8 aq1 = *(const bf16x8*)&Qb[(q0 + lr) * DK + 32 + lg * 8];

    float m_run[4], l_run[4];
    f32x4 acc_o[4];
    #pragma unroll
    for (int r = 0; r < 4; r++) { m_run[r] = -__builtin_inff(); l_run[r] = 0.0f; }
    #pragma unroll
    for (int nf = 0; nf < 4; nf++) acc_o[nf] = 0.0f;

    const int ktiles = (q0 + 47) >> 5;
    for (int kt = 0; kt < ktiles; ++kt) {
        const int kbase = kt * 32;
        f32x4 sf0 = 0.0f, sf1 = 0.0f;
        {
            bf16x8 bk;
            bk = *(const bf16x8*)&Kb[(kbase + lr) * DK + lg * 8];
            sf0 = __builtin_amdgcn_mfma_f32_16x16x32_bf16(aq0, bk, sf0, 0, 0, 0);
            bk = *(const bf16x8*)&Kb[(kbase + lr) * DK + 32 + lg * 8];
            sf0 = __builtin_amdgcn_mfma_f32_16x16x32_bf16(aq1, bk, sf0, 0, 0, 0);
            bk = *(const bf16x8*)&Kb[(kbase + 16 + lr) * DK + lg * 8];
            sf1 = __builtin_amdgcn_mfma_f32_16x16x32_bf16(aq0, bk, sf1, 0, 0, 0);
            bk = *(const bf16x8*)&Kb[(kbase + 16 + lr) * DK + 32 + lg * 8];
            sf1 = __builtin_amdgcn_mfma_f32_16x16x32_bf16(aq1, bk, sf1, 0, 0, 0);
        }

        float p[2][4], mt[4], scr[4], ts[4];
        #pragma unroll
        for (int r = 0; r < 4; r++) {
            int q = q0 + lg * 4 + r;
            float s0 = sf0[r] * 0.125f;
            float s1 = sf1[r] * 0.125f;
            if (kbase + lr > q)      s0 = -__builtin_inff();
            if (kbase + 16 + lr > q) s1 = -__builtin_inff();
            p[0][r] = s0; p[1][r] = s1;
            mt[r] = fmaxf(s0, s1);
        }
        #pragma unroll
        for (int off = 1; off < 16; off <<= 1)
            #pragma unroll
            for (int r = 0; r < 4; r++) mt[r] = fmaxf(mt[r], __shfl_xor(mt[r], off));
        #pragma unroll
        for (int r = 0; r < 4; r++) {
            float mn = fmaxf(m_run[r], mt[r]);
            scr[r] = __expf(m_run[r] - mn);
            m_run[r] = mn;
            float p0 = __expf(p[0][r] - mn);
            float p1 = __expf(p[1][r] - mn);
            p[0][r] = p0; p[1][r] = p1;
            ts[r] = p0 + p1;
            #pragma unroll
            for (int nf = 0; nf < 4; nf++) acc_o[nf][r] *= scr[r];
        }
        #pragma unroll
        for (int off = 1; off < 16; off <<= 1)
            #pragma unroll
            for (int r = 0; r < 4; r++) ts[r] += __shfl_xor(ts[r], off);
        #pragma unroll
        for (int r = 0; r < 4; r++) l_run[r] = l_run[r] * scr[r] + ts[r];

        // P -> A-fragment layout via wave-private swizzled LDS
        #pragma unroll
        for (int nf2 = 0; nf2 < 2; nf2++)
            #pragma unroll
            for (int r = 0; r < 4; r++) {
                int qrow = lg * 4 + r;
                int keyl = nf2 * 16 + lr;
                Pl[wid * 512 + qrow * 32 + (((keyl >> 3) ^ ((qrow >> 1) & 3)) << 3) + (keyl & 7)] = f2bf(p[nf2][r]);
            }
        asm volatile("s_waitcnt lgkmcnt(0)" ::: "memory");
        bf16x8 pa = *(const bf16x8*)&Pl[wid * 512 + lr * 32 + ((lg ^ ((lr >> 1) & 3)) << 3)];
        #pragma unroll
        for (int nf = 0; nf < 4; nf++) {
            bf16x8 bv = *(const bf16x8*)&Vb[(size_t)(nf * 16 + lr) * SEQ + kbase + lg * 8];
            acc_o[nf] = __builtin_amdgcn_mfma_f32_16x16x32_bf16(pa, bv, acc_o[nf], 0, 0, 0);
        }
    }

    #pragma unroll
    for (int r = 0; r < 4; r++) {
        float inv = 1.0f / l_run[r];
        int q = q0 + lg * 4 + r;
        #pragma unroll
        for (int nf = 0; nf < 4; nf++)
            aout[((size_t)b * SEQ + q) * D_MODEL + h * DK + nf * 16 + lr] = acc_o[nf][r] * inv;
    }
}

extern "C" void kernel_launch(void* const* d_in, const int* in_sizes, int n_in,
                              void* d_out, int out_size, void* d_ws, size_t ws_size,
                              hipStream_t stream) {
    const float* x    = (const float*)d_in[0];
    const int*   tpos = (const int*)d_in[1];
    const float* Wq   = (const float*)d_in[2];
    const float* Wk   = (const float*)d_in[3];
    const float* Wv   = (const float*)d_in[4];
    const float* Wo   = (const float*)d_in[5];
    float* out = (float*)d_out;

    char* ws = (char*)d_ws;
    float* cost = (float*)ws;                                  // 256 KB
    float* sint = (float*)(ws + 262144);                       // 256 KB
    unsigned short* Qb = (unsigned short*)(ws + 524288);       // 8 MB
    unsigned short* Kb = Qb + (size_t)4194304;                 // 8 MB
    unsigned short* VT = Kb + (size_t)4194304;                 // 8 MB
    float* attn = (float*)(ws + 524288 + (size_t)3 * 8388608); // 16 MB  (total ~41 MB)

    rope_tables_kernel<<<256, 256, 0, stream>>>(cost, sint);

    dim3 g(32, 8);
    gemm_kernel<0><<<g, 256, 0, stream>>>(x, Wq, Qb, tpos, cost, sint);
    gemm_kernel<0><<<g, 256, 0, stream>>>(x, Wk, Kb, tpos, cost, sint);
    gemm_kernel<1><<<g, 256, 0, stream>>>(x, Wv, VT, tpos, cost, sint);

    attn_kernel<<<dim3(32, NH, BATCH), 256, 0, stream>>>(Qb, Kb, VT, attn);

    gemm_kernel<2><<<g, 256, 0, stream>>>(attn, Wo, out, tpos, cost, sint);
}

// Round 2
// 234.106 us; speedup vs baseline: 1.7746x; 1.7746x over previous
//
#include <hip/hip_runtime.h>
#include <hip/hip_bf16.h>
#include <math.h>

#define D_MODEL 1024
#define NH      16
#define DK      64
#define SEQ     2048
#define BATCH   2

typedef float  f32x4  __attribute__((ext_vector_type(4)));
typedef __bf16 bf16x8 __attribute__((ext_vector_type(8)));
typedef unsigned short ushx4 __attribute__((ext_vector_type(4)));
typedef unsigned short ushx8 __attribute__((ext_vector_type(8)));
typedef unsigned short u16;

__device__ inline u16 f2bf(float f) {
    unsigned int u = __float_as_uint(f);
    u += 0x7FFFu + ((u >> 16) & 1u);   // round-to-nearest-even
    return (u16)(u >> 16);
}

// ---------------- RoPE tables: cos/sin [SEQ][DK/2] ----------------
__global__ void rope_tables_kernel(float* __restrict__ cost, float* __restrict__ sint) {
    int i = blockIdx.x * 256 + threadIdx.x;      // 2048*32 = 65536 total
    int pos = i >> 5, k = i & 31;
    float inv = powf(10000.0f, -2.0f * (float)k / 64.0f);
    float ang = (float)pos * inv;
    cost[i] = cosf(ang);
    sint[i] = sinf(ang);
}

// ---------------- fp32 -> bf16 converts ----------------
__global__ void cvt_kernel(const float* __restrict__ in, u16* __restrict__ out) {
    size_t i = ((size_t)blockIdx.x * 256 + threadIdx.x) * 8;
    f32x4 v0 = *(const f32x4*)(in + i);
    f32x4 v1 = *(const f32x4*)(in + i + 4);
    ushx4 o0, o1;
    #pragma unroll
    for (int e = 0; e < 4; e++) { o0[e] = f2bf(v0[e]); o1[e] = f2bf(v1[e]); }
    *(ushx4*)(out + i) = o0;
    *(ushx4*)(out + i + 4) = o1;
}

__global__ void cvtw_kernel(const float* __restrict__ wq, const float* __restrict__ wk,
                            const float* __restrict__ wv, const float* __restrict__ wo,
                            u16* __restrict__ oq, u16* __restrict__ ok,
                            u16* __restrict__ ov, u16* __restrict__ oo) {
    const float* in; u16* out;
    switch (blockIdx.y) {
        case 0: in = wq; out = oq; break;
        case 1: in = wk; out = ok; break;
        case 2: in = wv; out = ov; break;
        default: in = wo; out = oo; break;
    }
    size_t i = ((size_t)blockIdx.x * 256 + threadIdx.x) * 8;
    f32x4 v0 = *(const f32x4*)(in + i);
    f32x4 v1 = *(const f32x4*)(in + i + 4);
    ushx4 o0, o1;
    #pragma unroll
    for (int e = 0; e < 4; e++) { o0[e] = f2bf(v0[e]); o1[e] = f2bf(v1[e]); }
    *(ushx4*)(out + i) = o0;
    *(ushx4*)(out + i + 4) = o1;
}

// ---------------- GEMM: C[m][n] = sum_k A[m][k] * W[n][k], bf16 inputs ----------------
// MODE 0: RoPE epilogue, store bf16 [b][h][s][dk]
// MODE 1: store bf16 V^T  [b][h][dk][s]
// MODE 2: store fp32 [m][n]
template<int MODE>
__global__ __launch_bounds__(256) void gemm_kernel(
    const u16* __restrict__ A, const u16* __restrict__ W,
    void* __restrict__ outp, const int* __restrict__ tpos,
    const float* __restrict__ cost, const float* __restrict__ sint)
{
    constexpr int K = 1024;
    __shared__ u16 As[128 * 32];
    __shared__ u16 Bs[128 * 32];

    const int t  = threadIdx.x;
    const int m0 = blockIdx.x * 128, n0 = blockIdx.y * 128;
    const int lane = t & 63, wid = t >> 6;
    const int wm = wid >> 1, wn = wid & 1;       // 2x2 wave grid, 64x64 per wave
    const int lr = lane & 15, lg = lane >> 4;
    const int srow = t >> 1, scolb = (t & 1) * 16;

    f32x4 acc[4][4];
    #pragma unroll
    for (int i = 0; i < 4; i++)
        #pragma unroll
        for (int j = 0; j < 4; j++) acc[i][j] = 0.0f;

    const u16* Arow = A + (size_t)(m0 + srow) * K + scolb;
    const u16* Wrow = W + (size_t)(n0 + srow) * K + scolb;
    const int swzS = (srow >> 1) & 3;
    const int c0 = (t & 1) * 2;
    const int sa0 = srow * 32 + ((c0 ^ swzS) << 3);
    const int sa1 = srow * 32 + (((c0 + 1) ^ swzS) << 3);

    for (int k0 = 0; k0 < K; k0 += 32) {
        __syncthreads();
        ushx8 a0 = *(const ushx8*)(Arow + k0);
        ushx8 a1 = *(const ushx8*)(Arow + k0 + 8);
        ushx8 w0 = *(const ushx8*)(Wrow + k0);
        ushx8 w1 = *(const ushx8*)(Wrow + k0 + 8);
        *(ushx8*)&As[sa0] = a0; *(ushx8*)&As[sa1] = a1;
        *(ushx8*)&Bs[sa0] = w0; *(ushx8*)&Bs[sa1] = w1;
        __syncthreads();

        bf16x8 af[4], bfr[4];
        #pragma unroll
        for (int mi = 0; mi < 4; mi++) {
            int row = wm * 64 + mi * 16 + lr;
            af[mi] = *(const bf16x8*)&As[row * 32 + ((lg ^ ((row >> 1) & 3)) << 3)];
        }
        #pragma unroll
        for (int ni = 0; ni < 4; ni++) {
            int row = wn * 64 + ni * 16 + lr;
            bfr[ni] = *(const bf16x8*)&Bs[row * 32 + ((lg ^ ((row >> 1) & 3)) << 3)];
        }
        #pragma unroll
        for (int mi = 0; mi < 4; mi++)
            #pragma unroll
            for (int ni = 0; ni < 4; ni++)
                acc[mi][ni] = __builtin_amdgcn_mfma_f32_16x16x32_bf16(af[mi], bfr[ni], acc[mi][ni], 0, 0, 0);
    }

    #pragma unroll
    for (int mi = 0; mi < 4; mi++)
        #pragma unroll
        for (int ni = 0; ni < 4; ni++) {
            f32x4 v4 = acc[mi][ni];
            #pragma unroll
            for (int r = 0; r < 4; r++) {
                int m = m0 + wm * 64 + mi * 16 + lg * 4 + r;
                int n = n0 + wn * 64 + ni * 16 + lr;
                float v = v4[r];
                if constexpr (MODE == 2) {
                    ((float*)outp)[(size_t)m * D_MODEL + n] = v;
                } else if constexpr (MODE == 1) {
                    int b = m >> 11, s = m & 2047;
                    int h = n >> 6,  d = n & 63;
                    ((u16*)outp)[(((size_t)b * NH + h) * DK + d) * SEQ + s] = f2bf(v);
                } else {
                    float vp = __shfl_xor(v, 1);   // pair partner (n parity == lane parity)
                    int b = m >> 11, s = m & 2047;
                    int h = n >> 6,  d = n & 63;
                    int tp = tpos[s];
                    float c  = cost[tp * 32 + (d >> 1)];
                    float sn = sint[tp * 32 + (d >> 1)];
                    float res = (d & 1) ? (vp * sn + v * c) : (v * c - vp * sn);
                    ((u16*)outp)[(((size_t)b * NH + h) * SEQ + s) * DK + d] = f2bf(res);
                }
            }
        }
}

// ---------------- causal flash attention ----------------
// Q,K bf16 [b][h][s][dk]; VT bf16 [b][h][dk][s]; out bf16 [b][s][h*dk]
// 32 q-rows per wave (2 row groups), KVBLK=32, reg double-buffered K/V prefetch.
struct KVt { bf16x8 k[2][2]; bf16x8 v[4]; };

__global__ __launch_bounds__(256, 2) void attn_kernel(
    const u16* __restrict__ Q,
    const u16* __restrict__ Km,
    const u16* __restrict__ VT,
    u16* __restrict__ aout)
{
    __shared__ u16 Pl[4][32 * 32];               // per-wave 32x32 P tile (8 KB)
    const int t = threadIdx.x, wid = t >> 6, lane = t & 63;
    const int lr = lane & 15, lg = lane >> 4;
    const int item = wid * 512 + blockIdx.x;     // balanced spread: block gets q-tiles {q,q+16,q+32,q+48}
    const int bh = item & 31;
    const int qt = item >> 5;                    // 0..63
    const int q0 = qt * 32;
    const int b = bh >> 4, h = bh & 15;

    const u16* Qb = Q  + (size_t)bh * SEQ * DK;
    const u16* Kb = Km + (size_t)bh * SEQ * DK;
    const u16* Vb = VT + (size_t)bh * DK * SEQ;
    u16* Plw = Pl[wid];

    bf16x8 aq[2][2];
    #pragma unroll
    for (int g = 0; g < 2; g++)
        #pragma unroll
        for (int h2 = 0; h2 < 2; h2++)
            aq[g][h2] = *(const bf16x8*)&Qb[(q0 + g * 16 + lr) * DK + h2 * 32 + lg * 8];

    float m_run[2][4], l_run[2][4];
    f32x4 acc_o[2][4];
    #pragma unroll
    for (int g = 0; g < 2; g++)
        #pragma unroll
        for (int r = 0; r < 4; r++) { m_run[g][r] = -__builtin_inff(); l_run[g][r] = 0.0f; }
    #pragma unroll
    for (int g = 0; g < 2; g++)
        #pragma unroll
        for (int dg = 0; dg < 4; dg++) acc_o[g][dg] = 0.0f;

    auto loadKV = [&](KVt& kv, int kbase) {
        #pragma unroll
        for (int kg = 0; kg < 2; kg++)
            #pragma unroll
            for (int h2 = 0; h2 < 2; h2++)
                kv.k[kg][h2] = *(const bf16x8*)&Kb[(kbase + kg * 16 + lr) * DK + h2 * 32 + lg * 8];
        #pragma unroll
        for (int dg = 0; dg < 4; dg++)
            kv.v[dg] = *(const bf16x8*)&Vb[(size_t)(dg * 16 + lr) * SEQ + kbase + lg * 8];
    };

    auto tile = [&](const KVt& kv, int kbase) {
        f32x4 sf[2][2];
        #pragma unroll
        for (int g = 0; g < 2; g++)
            #pragma unroll
            for (int kg = 0; kg < 2; kg++) sf[g][kg] = 0.0f;
        __builtin_amdgcn_s_setprio(1);
        #pragma unroll
        for (int g = 0; g < 2; g++)
            #pragma unroll
            for (int kg = 0; kg < 2; kg++) {
                sf[g][kg] = __builtin_amdgcn_mfma_f32_16x16x32_bf16(aq[g][0], kv.k[kg][0], sf[g][kg], 0, 0, 0);
                sf[g][kg] = __builtin_amdgcn_mfma_f32_16x16x32_bf16(aq[g][1], kv.k[kg][1], sf[g][kg], 0, 0, 0);
            }
        __builtin_amdgcn_s_setprio(0);

        #pragma unroll
        for (int g = 0; g < 2; g++) {
            float mt[4], scr[4], ts[4], p0a[4], p1a[4];
            #pragma unroll
            for (int r = 0; r < 4; r++) {
                int q = q0 + g * 16 + lg * 4 + r;
                float s0 = sf[g][0][r] * 0.125f;
                float s1 = sf[g][1][r] * 0.125f;
                if (kbase + lr > q)      s0 = -__builtin_inff();
                if (kbase + 16 + lr > q) s1 = -__builtin_inff();
                p0a[r] = s0; p1a[r] = s1;
                mt[r] = fmaxf(s0, s1);
            }
            #pragma unroll
            for (int off = 1; off < 16; off <<= 1)
                #pragma unroll
                for (int r = 0; r < 4; r++) mt[r] = fmaxf(mt[r], __shfl_xor(mt[r], off));
            #pragma unroll
            for (int r = 0; r < 4; r++) {
                float mn = fmaxf(m_run[g][r], mt[r]);
                scr[r] = __expf(m_run[g][r] - mn);
                m_run[g][r] = mn;
                float p0 = __expf(p0a[r] - mn);
                float p1 = __expf(p1a[r] - mn);
                ts[r] = p0 + p1;
                #pragma unroll
                for (int dg = 0; dg < 4; dg++) acc_o[g][dg][r] *= scr[r];
                int qrow = g * 16 + lg * 4 + r;
                int sz = (qrow >> 1) & 3;
                Plw[qrow * 32 + (((lr >> 3) ^ sz) << 3) + (lr & 7)]       = f2bf(p0);
                Plw[qrow * 32 + (((2 + (lr >> 3)) ^ sz) << 3) + (lr & 7)] = f2bf(p1);
            }
            #pragma unroll
            for (int off = 1; off < 16; off <<= 1)
                #pragma unroll
                for (int r = 0; r < 4; r++) ts[r] += __shfl_xor(ts[r], off);
            #pragma unroll
            for (int r = 0; r < 4; r++) l_run[g][r] = l_run[g][r] * scr[r] + ts[r];
        }

        asm volatile("s_waitcnt lgkmcnt(0)" ::: "memory");
        bf16x8 pa[2];
        #pragma unroll
        for (int g = 0; g < 2; g++) {
            int row = g * 16 + lr;
            pa[g] = *(const bf16x8*)&Plw[row * 32 + ((lg ^ ((row >> 1) & 3)) << 3)];
        }
        __builtin_amdgcn_s_setprio(1);
        #pragma unroll
        for (int g = 0; g < 2; g++)
            #pragma unroll
            for (int dg = 0; dg < 4; dg++)
                acc_o[g][dg] = __builtin_amdgcn_mfma_f32_16x16x32_bf16(pa[g], kv.v[dg], acc_o[g][dg], 0, 0, 0);
        __builtin_amdgcn_s_setprio(0);
    };

    const int ktiles = qt + 1;
    KVt bufA, bufB;
    loadKV(bufA, 0);
    int kt = 0;
    for (;;) {
        if (kt + 1 < ktiles) loadKV(bufB, (kt + 1) * 32);
        tile(bufA, kt * 32);
        if (++kt >= ktiles) break;
        if (kt + 1 < ktiles) loadKV(bufA, (kt + 1) * 32);
        tile(bufB, kt * 32);
        if (++kt >= ktiles) break;
    }

    #pragma unroll
    for (int g = 0; g < 2; g++)
        #pragma unroll
        for (int r = 0; r < 4; r++) {
            float inv = 1.0f / l_run[g][r];
            int q = q0 + g * 16 + lg * 4 + r;
            #pragma unroll
            for (int dg = 0; dg < 4; dg++)
                aout[((size_t)b * SEQ + q) * D_MODEL + h * DK + dg * 16 + lr] = f2bf(acc_o[g][dg][r] * inv);
        }
}

extern "C" void kernel_launch(void* const* d_in, const int* in_sizes, int n_in,
                              void* d_out, int out_size, void* d_ws, size_t ws_size,
                              hipStream_t stream) {
    const float* x    = (const float*)d_in[0];
    const int*   tpos = (const int*)d_in[1];
    const float* Wq   = (const float*)d_in[2];
    const float* Wk   = (const float*)d_in[3];
    const float* Wv   = (const float*)d_in[4];
    const float* Wo   = (const float*)d_in[5];
    float* out = (float*)d_out;

    char* ws = (char*)d_ws;
    float* cost = (float*)ws;                                   // 256 KB
    float* sint = (float*)(ws + (256 << 10));                   // 256 KB
    u16* Qb   = (u16*)(ws + (512 << 10));                       // 8 MB
    u16* Kb   = (u16*)(ws + (512 << 10) + ((size_t)8  << 20));  // 8 MB
    u16* VT   = (u16*)(ws + (512 << 10) + ((size_t)16 << 20));  // 8 MB
    u16* xb   = (u16*)(ws + (512 << 10) + ((size_t)24 << 20));  // 8 MB (reused as attnb)
    u16* Wqb  = (u16*)(ws + (512 << 10) + ((size_t)32 << 20));  // 2 MB
    u16* Wkb  = (u16*)(ws + (512 << 10) + ((size_t)34 << 20));
    u16* Wvb  = (u16*)(ws + (512 << 10) + ((size_t)36 << 20));
    u16* Wob  = (u16*)(ws + (512 << 10) + ((size_t)38 << 20));  // total 40.5 MB
    u16* attnb = xb;   // x no longer needed once Q/K/V GEMMs are done (stream-ordered)

    rope_tables_kernel<<<256, 256, 0, stream>>>(cost, sint);
    cvt_kernel<<<2048, 256, 0, stream>>>(x, xb);
    cvtw_kernel<<<dim3(512, 4), 256, 0, stream>>>(Wq, Wk, Wv, Wo, Wqb, Wkb, Wvb, Wob);

    dim3 g(32, 8);
    gemm_kernel<0><<<g, 256, 0, stream>>>(xb, Wqb, Qb, tpos, cost, sint);
    gemm_kernel<0><<<g, 256, 0, stream>>>(xb, Wkb, Kb, tpos, cost, sint);
    gemm_kernel<1><<<g, 256, 0, stream>>>(xb, Wvb, VT, tpos, cost, sint);

    attn_kernel<<<512, 256, 0, stream>>>(Qb, Kb, VT, attnb);

    gemm_kernel<2><<<g, 256, 0, stream>>>(attnb, Wob, out, tpos, cost, sint);
}